// Round 14
// baseline (69.720 us; speedup 1.0000x reference)
//
#include <hip/hip_runtime.h>
#include <hip/hip_bf16.h>
#include <math.h>

typedef short bf16x8 __attribute__((ext_vector_type(8)));
typedef float f32x4  __attribute__((ext_vector_type(4)));

static __device__ __forceinline__ unsigned short f2bf(float x) {
    unsigned u = __builtin_bit_cast(unsigned, x);
    return (unsigned short)((u + 0x7fffu + ((u >> 16) & 1u)) >> 16);
}

static __device__ __forceinline__ bf16x8 pack8(float4 u0, float4 u1) {
    bf16x8 f;
    f[0] = (short)f2bf(u0.x); f[1] = (short)f2bf(u0.y);
    f[2] = (short)f2bf(u0.z); f[3] = (short)f2bf(u0.w);
    f[4] = (short)f2bf(u1.x); f[5] = (short)f2bf(u1.y);
    f[6] = (short)f2bf(u1.z); f[7] = (short)f2bf(u1.w);
    return f;
}

// ---- cent_prep: blocks [0,nblk): bf16 image + c2; block nblk: zero + detect -
// img[cb16][k][lane][j] = cent[cb16*16 + (lane&15)][k*32 + (lane>>4)*8 + j]
__global__ __launch_bounds__(256) void cent_prep_kernel(
    const float* __restrict__ cent, char* __restrict__ Cimg,
    float* __restrict__ c2g, const unsigned* __restrict__ w, int nelem,
    unsigned* __restrict__ flag, float* __restrict__ out, int out_size,
    int ncb, int nblk) {
    const int tid = threadIdx.x, lane = tid & 63, wv = tid >> 6;
    if ((int)blockIdx.x < nblk) {
        const int cb = blockIdx.x * 4 + wv;
        if (cb < ncb) {
            const int r = cb * 16 + (lane & 15);
            const int q = lane >> 4;
            const float4* C4 = (const float4*)cent;
            float s = 0.0f;
            #pragma unroll
            for (int k = 0; k < 8; ++k) {
                int fidx = r * 64 + k * 8 + q * 2;
                float4 u0 = C4[fidx], u1 = C4[fidx + 1];
                *(bf16x8*)(Cimg + ((size_t)(cb * 8 + k) * 64 + lane) * 16) = pack8(u0, u1);
                s += u0.x*u0.x + u0.y*u0.y + u0.z*u0.z + u0.w*u0.w
                   + u1.x*u1.x + u1.y*u1.y + u1.z*u1.z + u1.w*u1.w;
            }
            s += __shfl_xor(s, 16, 64);
            s += __shfl_xor(s, 32, 64);
            if (lane < 16) c2g[cb * 16 + lane] = s;
        }
    } else {
        // label-width detect (sample first 4096 pairs) + zero the output
        int npairs = nelem / 2; if (npairs > 4096) npairs = 4096;
        unsigned accw = 0;
        for (int i = tid; i < npairs; i += 256) accw |= w[2 * i + 1];
        #pragma unroll
        for (int d = 32; d >= 1; d >>= 1) accw |= __shfl_xor(accw, d, 64);
        if (lane == 0) atomicOr(flag, accw != 0u ? 1u : 0u);
        for (int i = tid; i < out_size; i += 256) out[i] = 0.0f;
    }
}

// ---- main10: TLP-first. 1024 blocks x 256 thr; wave = 16 rows x 16 cols. ----
// Per-wave state minimized (a[8]=32 VGPR, b[8]=32, acc=4; live ~110 < 128) so
// __launch_bounds__(256,4) gives 4 waves/SIMD = 16 waves/CU (4 blocks/CU).
// Grid col-split 2-way: block = 64 rows x K/2 cols. B-fragments L2->registers,
// no LDS, no barriers; TLP hides load latency (R11-R13 lesson: 1-2 waves/SIMD
// + any pipelining scheme stalls at 42-55us; occupancy was the constraint).
// pos from MFMA dot (validated R10-R13, absmax 0.0); d2=-2*acc; screen d2<2.
__global__ __launch_bounds__(256, 4) void main10_kernel(
    const float* __restrict__ emb, const char* __restrict__ Cimg,
    const float* __restrict__ c2g, const int* __restrict__ labw,
    const unsigned* __restrict__ flag, float* __restrict__ out,
    int nchalf, float invB) {
    __shared__ float red[4];

    const int tid = threadIdx.x, lane = tid & 63, wid = tid >> 6;
    const int brow0 = (blockIdx.x >> 1) * 64;       // 64-row group
    const int cb0 = (blockIdx.x & 1) * nchalf;      // col-half (in cb16 units)
    const int l15 = lane & 15, q = lane >> 4;

    const int is32 = (*flag != 0u);
    const int rg = brow0 + wid * 16 + l15;          // this wave's row (by l15)
    const int lab_self = is32 ? labw[rg] : labw[2 * rg];

    // A: 16 rows/wave -> bf16 fragments (32 VGPR); e2 via 2 shfl_xor
    bf16x8 a[8];
    float s = 0.0f;
    {
        const float4* E4 = (const float4*)emb + (size_t)rg * 64;
        #pragma unroll
        for (int k = 0; k < 8; ++k) {
            float4 u0 = E4[k * 8 + q * 2], u1 = E4[k * 8 + q * 2 + 1];
            a[k] = pack8(u0, u1);
            s += u0.x*u0.x + u0.y*u0.y + u0.z*u0.z + u0.w*u0.w
               + u1.x*u1.x + u1.y*u1.y + u1.z*u1.z + u1.w*u1.w;
        }
        s += __shfl_xor(s, 16, 64);
        s += __shfl_xor(s, 32, 64);                 // full e2 of row l15
    }
    // acc-row r = global row wid*16 + q*4 + r
    float ainit[4]; int lb[4];
    #pragma unroll
    for (int r = 0; r < 4; ++r) {
        ainit[r] = -0.5f * __shfl(s, q * 4 + r, 64);
        lb[r] = __shfl(lab_self, q * 4 + r, 64);
    }

    float fsum = 0.0f;

    for (int g = 0; g < nchalf; ++g) {
        const int cb = cb0 + g;
        const char* Bp = Cimg + (size_t)cb * 8192 + lane * 16;
        bf16x8 b[8];
        #pragma unroll
        for (int k = 0; k < 8; ++k)
            b[k] = *(const bf16x8*)(Bp + k * 1024);
        const float c2v = -0.5f * c2g[cb * 16 + l15];

        f32x4 acc;
        #pragma unroll
        for (int r = 0; r < 4; ++r) acc[r] = ainit[r] + c2v;
        #pragma unroll
        for (int k = 0; k < 8; ++k)
            acc = __builtin_amdgcn_mfma_f32_16x16x32_bf16(a[k], b[k], acc, 0, 0, 0);

        const int colg = cb * 16 + l15;
        float mx = -3.0e38f;
        #pragma unroll
        for (int r = 0; r < 4; ++r) {
            fsum += (colg == lb[r]) ? fmaxf(-2.0f * acc[r], 0.0f) : 0.0f;
            mx = fmaxf(mx, acc[r]);
        }
        if (__builtin_expect(__any(mx > -1.0f), 0)) {   // rare: d2 < 2 slack
            #pragma unroll
            for (int r = 0; r < 4; ++r) {
                float d2 = fmaxf(-2.0f * acc[r], 0.0f);
                if (d2 < 1.0f && colg != lb[r]) {
                    float tt = 1.0f - sqrtf(d2);
                    fsum += tt * tt;
                }
            }
        }
    }

    #pragma unroll
    for (int d = 32; d >= 1; d >>= 1) fsum += __shfl_xor(fsum, d, 64);
    if (lane == 0) red[wid] = fsum;
    __syncthreads();
    if (tid == 0)
        atomicAdd(out, (red[0] + red[1] + red[2] + red[3]) * invB);
}

// ======================= fallback (round-1, verified) ========================
#define FB_THREADS 512
#define FB_SMEM 132672
__device__ int g_lab_is64;

__global__ void fb_detect_kernel(const unsigned* __restrict__ w, int nelem,
                                 float* __restrict__ out, int out_size) {
    __shared__ unsigned red[256];
    unsigned acc = 0;
    for (int i = threadIdx.x; i < nelem / 2; i += 256) acc |= w[2 * i + 1];
    red[threadIdx.x] = acc;
    __syncthreads();
    for (int s = 128; s > 0; s >>= 1) {
        if (threadIdx.x < s) red[threadIdx.x] |= red[threadIdx.x + s];
        __syncthreads();
    }
    if (threadIdx.x == 0) g_lab_is64 = (red[0] == 0u) ? 1 : 0;
    for (int i = threadIdx.x; i < out_size; i += 256) out[i] = 0.0f;
}

__global__ __launch_bounds__(FB_THREADS) void fb_loss_kernel(
    const float* __restrict__ emb, const float* __restrict__ cent,
    const int* __restrict__ labw, float* __restrict__ out,
    int nchunk, float invB) {
    extern __shared__ char smem[];
    char* Abf = smem;
    char* Cbf = smem + 65536;
    float* e2 = (float*)(smem + 131072);
    float* c2 = (float*)(smem + 131584);
    int* lab = (int*)(smem + 132096);
    float* red = (float*)(smem + 132608);

    const int tid = threadIdx.x, lane = tid & 63, wid = tid >> 6;
    const int row0 = blockIdx.x * 128;
    const int is64 = g_lab_is64;

    for (int j = 0; j < 16; ++j) {
        int f4 = tid + j * FB_THREADS;
        int r = f4 >> 6, c4 = f4 & 63;
        float4 v = ((const float4*)emb)[(size_t)(row0 + r) * 64 + c4];
        ushort4 h;
        h.x = f2bf(v.x); h.y = f2bf(v.y); h.z = f2bf(v.z); h.w = f2bf(v.w);
        int off = (c4 * 8) ^ ((r & 7) << 4);
        *(ushort4*)(Abf + r * 512 + off) = h;
        float s = v.x*v.x + v.y*v.y + v.z*v.z + v.w*v.w;
        #pragma unroll
        for (int m = 32; m >= 1; m >>= 1) s += __shfl_xor(s, m, 64);
        if (lane == 0) e2[r] = s;
    }
    if (tid < 128) {
        int b = row0 + tid;
        lab[tid] = is64 ? labw[2 * b] : labw[b];
    }
    __syncthreads();

    const int wr = wid >> 1, wc = wid & 1;
    const int l15 = lane & 15, l16 = lane >> 4;
    const int swz = (l15 & 7) << 4;

    float e2v[2][4]; int labv[2][4];
    #pragma unroll
    for (int m = 0; m < 2; ++m)
        #pragma unroll
        for (int r = 0; r < 4; ++r) {
            int rr = wr * 32 + m * 16 + l16 * 4 + r;
            e2v[m][r] = e2[rr]; labv[m][r] = lab[rr];
        }

    float fsum = 0.0f;
    for (int ch = 0; ch < nchunk; ++ch) {
        const float* cbase = cent + (size_t)ch * 128 * 256;
        for (int j = 0; j < 16; ++j) {
            int f4 = tid + j * FB_THREADS;
            int r = f4 >> 6, c4 = f4 & 63;
            float4 v = ((const float4*)cbase)[(size_t)r * 64 + c4];
            ushort4 h;
            h.x = f2bf(v.x); h.y = f2bf(v.y); h.z = f2bf(v.z); h.w = f2bf(v.w);
            int off = (c4 * 8) ^ ((r & 7) << 4);
            *(ushort4*)(Cbf + r * 512 + off) = h;
            float s = v.x*v.x + v.y*v.y + v.z*v.z + v.w*v.w;
            #pragma unroll
            for (int m = 32; m >= 1; m >>= 1) s += __shfl_xor(s, m, 64);
            if (lane == 0) c2[r] = s;
        }
        __syncthreads();

        f32x4 acc[2][4];
        #pragma unroll
        for (int m = 0; m < 2; ++m)
            #pragma unroll
            for (int n = 0; n < 4; ++n) acc[m][n] = (f32x4){0, 0, 0, 0};

        #pragma unroll
        for (int kk = 0; kk < 8; ++kk) {
            int kb = kk * 64 + l16 * 16;
            bf16x8 a[2], b[4];
            #pragma unroll
            for (int m = 0; m < 2; ++m)
                a[m] = *(const bf16x8*)(Abf + (wr * 32 + m * 16 + l15) * 512 + (kb ^ swz));
            #pragma unroll
            for (int n = 0; n < 4; ++n)
                b[n] = *(const bf16x8*)(Cbf + (wc * 64 + n * 16 + l15) * 512 + (kb ^ swz));
            #pragma unroll
            for (int m = 0; m < 2; ++m)
                #pragma unroll
                for (int n = 0; n < 4; ++n)
                    acc[m][n] = __builtin_amdgcn_mfma_f32_16x16x32_bf16(a[m], b[n], acc[m][n], 0, 0, 0);
        }

        float c2v[4]; int colg[4];
        #pragma unroll
        for (int n = 0; n < 4; ++n) {
            int cl = wc * 64 + n * 16 + l15;
            c2v[n] = c2[cl]; colg[n] = ch * 128 + cl;
        }
        unsigned need = 0;
        #pragma unroll
        for (int m = 0; m < 2; ++m)
            #pragma unroll
            for (int n = 0; n < 4; ++n)
                #pragma unroll
                for (int r = 0; r < 4; ++r) {
                    float d2 = fmaf(-2.0f, acc[m][n][r], e2v[m][r] + c2v[n]);
                    d2 = fmaxf(d2, 0.0f);
                    bool isp = (colg[n] == labv[m][r]);
                    fsum += isp ? d2 : 0.0f;
                    need |= (unsigned)((!isp) & (d2 < 1.0f)) << (m * 16 + n * 4 + r);
                }
        if (__any(need != 0)) {
            #pragma unroll
            for (int m = 0; m < 2; ++m)
                #pragma unroll
                for (int n = 0; n < 4; ++n)
                    #pragma unroll
                    for (int r = 0; r < 4; ++r)
                        if ((need >> (m * 16 + n * 4 + r)) & 1u) {
                            float d2 = fmaf(-2.0f, acc[m][n][r], e2v[m][r] + c2v[n]);
                            d2 = fmaxf(d2, 0.0f);
                            float t = 1.0f - sqrtf(d2);
                            fsum += t * t;
                        }
        }
        __syncthreads();
    }
    #pragma unroll
    for (int m = 32; m >= 1; m >>= 1) fsum += __shfl_xor(fsum, m, 64);
    if (lane == 0) red[wid] = fsum;
    __syncthreads();
    if (tid == 0) {
        float t = 0.0f;
        #pragma unroll
        for (int w = 0; w < 8; ++w) t += red[w];
        atomicAdd(out, t * invB);
    }
}

// =============================================================================
extern "C" void kernel_launch(void* const* d_in, const int* in_sizes, int n_in,
                              void* d_out, int out_size, void* d_ws, size_t ws_size,
                              hipStream_t stream) {
    const float* emb = (const float*)d_in[0];
    const float* cent = (const float*)d_in[1];
    const int* labw = (const int*)d_in[2];
    float* out = (float*)d_out;

    const int B = in_sizes[0] / 256;
    const int K = in_sizes[1] / 256;
    const float invB = 1.0f / (float)B;

    char* ws = (char*)d_ws;
    const size_t off_flag = 0;
    const size_t off_c2 = 4096;                          // K floats
    const size_t off_cimg = off_c2 + (((size_t)K * 4 + 4095) & ~(size_t)4095);
    const size_t req = off_cimg + (size_t)K * 512;

    if (ws_size >= req && K >= 64 && (K % 32) == 0 && (B % 64) == 0) {
        hipMemsetAsync(ws + off_flag, 0, 4, stream);     // tiny, graph-safe
        const int ncb = K / 16;                          // col-blocks of 16
        const int nblk = (ncb + 3) / 4;                  // image blocks
        cent_prep_kernel<<<nblk + 1, 256, 0, stream>>>(
            cent, ws + off_cimg, (float*)(ws + off_c2),
            (const unsigned*)d_in[2], in_sizes[2], (unsigned*)(ws + off_flag),
            out, out_size, ncb, nblk);

        main10_kernel<<<(B / 64) * 2, 256, 0, stream>>>(
            emb, ws + off_cimg, (const float*)(ws + off_c2), labw,
            (const unsigned*)(ws + off_flag), out, K / 32, invB);
    } else {
        fb_detect_kernel<<<1, 256, 0, stream>>>((const unsigned*)d_in[2], in_sizes[2],
                                                out, out_size);
        hipFuncSetAttribute(reinterpret_cast<const void*>(fb_loss_kernel),
                            hipFuncAttributeMaxDynamicSharedMemorySize, FB_SMEM);
        fb_loss_kernel<<<B / 128, FB_THREADS, FB_SMEM, stream>>>(
            emb, cent, labw, out, K / 128, invB);
    }
}